// Round 6
// baseline (185.963 us; speedup 1.0000x reference)
//
#include <hip/hip_runtime.h>

// Problem: B=2, S=2048, D=1024, H=16, HD=64. fp32 in/out.
// Pipeline exploits head-summed K/V: k_sum = x @ (sum_h Wk_h)^T + sum_h bk_h.
//  1. prep_all:    x, Wout -> f16; wcomb = [Wq; Wred] f16 (1152x1024); bcomb
//  2. gemm_big<0>: [Q*scale | k_sum | v_sum^T] = x @ wcomb^T + bcomb  (N=1152)
//  3. flash_attn6: 32x32x16 mfma, 2 s packed in B-cols, shuffle P-transform
//  4. gemm_big<1>: out = ao @ Wout^T + bout   (4096x1024x1024) -> f32

#define S_LEN 2048
#define DIM 1024

using floatx4  = __attribute__((ext_vector_type(4))) float;
using floatx16 = __attribute__((ext_vector_type(16))) float;
using halfx8   = __attribute__((ext_vector_type(8))) _Float16;
using halfx4   = __attribute__((ext_vector_type(4))) _Float16;

__device__ __forceinline__ floatx4 mfma16(halfx8 a, halfx8 b, floatx4 c) {
  return __builtin_amdgcn_mfma_f32_16x16x32_f16(a, b, c, 0, 0, 0);
}
__device__ __forceinline__ floatx16 mfma32(halfx8 a, halfx8 b, floatx16 c) {
  return __builtin_amdgcn_mfma_f32_32x32x16_f16(a, b, c, 0, 0, 0);
}

// async global->LDS, 16B per lane; lds dst is wave-uniform base + lane*16
__device__ __forceinline__ void gll16(const void* g, void* l) {
  __builtin_amdgcn_global_load_lds(
      (const __attribute__((address_space(1))) void*)g,
      (__attribute__((address_space(3))) void*)l, 16, 0, 0);
}

// ---------------- prep: conversions + combined weights ----------------
__global__ __launch_bounds__(256) void prep_all(
    const float* __restrict__ x, const float* __restrict__ wqkv,
    const float* __restrict__ bqkv, const float* __restrict__ wout,
    _Float16* __restrict__ xb, _Float16* __restrict__ wcomb,
    _Float16* __restrict__ woutb, float* __restrict__ bcomb) {
  int bx = blockIdx.x;
  if (bx < 6144) {
    size_t i4 = ((size_t)bx * 256 + threadIdx.x) * 4;
    const float* src;
    _Float16* dst;
    size_t off;
    if (i4 < 4194304) { src = x; dst = xb; off = i4; }
    else if (i4 < 5242880) { src = wqkv; dst = wcomb; off = i4 - 4194304; }
    else { src = wout; dst = woutb; off = i4 - 5242880; }
    float4 v = *(const float4*)(src + off);
    halfx4 o;
    o[0] = (_Float16)v.x; o[1] = (_Float16)v.y;
    o[2] = (_Float16)v.z; o[3] = (_Float16)v.w;
    *(halfx4*)(dst + off) = o;
  } else {
    int gid = (bx - 6144) * 256 + threadIdx.x;  // 131072 threads
    int c = gid >> 10, j = gid & 1023;
    int row0 = (c < 64) ? (1024 + c) : (2048 + c - 64);
    float s = 0.f;
#pragma unroll
    for (int h = 0; h < 16; ++h) s += wqkv[(size_t)(row0 + h * 64) * 1024 + j];
    wcomb[(size_t)1024 * 1024 + gid] = (_Float16)s;
    if (gid < 1024) bcomb[gid] = bqkv[gid];
    if (gid < 128) {
      int b0 = (gid < 64) ? (1024 + gid) : (2048 + gid - 64);
      float sb = 0.f;
#pragma unroll
      for (int h = 0; h < 16; ++h) sb += bqkv[b0 + h * 64];
      bcomb[1024 + gid] = sb;
    }
  }
}

// ---------------- gemm_big: 64M x 128N, BK=64, dbuf LDS, 1 barrier/iter ----
// Both A and W staged via gll16 (XOR swizzle), double-buffered.
// MODE 0: N=1152 fused epilogue -> qb (cols<1024, *softmax-scale), kb, vtb.
// MODE 1: N=1024, f32 out.
template <int MODE>
__global__ __launch_bounds__(256, 2) void gemm_big(
    const _Float16* __restrict__ A, const _Float16* __restrict__ W,
    const float* __restrict__ bias, void* __restrict__ Cv,
    _Float16* __restrict__ kbo, _Float16* __restrict__ vto) {
  const int K = 1024;
  __shared__ _Float16 As[2][64][64];    // 16 KB
  __shared__ _Float16 Ws[2][128][64];   // 32 KB
  int tid = threadIdx.x;
  int lane = tid & 63, w = tid >> 6, ln = lane & 15, q4 = lane >> 4;
  int m0 = blockIdx.x * 64, n0 = blockIdx.y * 128;
  int rr = lane >> 3, gg = ((lane & 7) ^ rr) * 8;
  const _Float16* agp = A + (size_t)(m0 + 16 * w + rr) * K + gg;
  const _Float16* wgp = W + (size_t)(n0 + 32 * w + rr) * K + gg;
  floatx4 acc[4][2] = {};
  // prologue: stage buf0
  gll16(agp, &As[0][16 * w][0]);
  gll16(agp + (size_t)8 * K, &As[0][16 * w + 8][0]);
#pragma unroll
  for (int j = 0; j < 4; ++j)
    gll16(wgp + (size_t)(8 * j) * K, &Ws[0][32 * w + 8 * j][0]);
  __syncthreads();
  for (int kt = 0; kt < K; kt += 64) {
    int cur = (kt >> 6) & 1;
    if (kt + 64 < K) {
      gll16(agp + kt + 64, &As[cur ^ 1][16 * w][0]);
      gll16(agp + (size_t)8 * K + kt + 64, &As[cur ^ 1][16 * w + 8][0]);
#pragma unroll
      for (int j = 0; j < 4; ++j)
        gll16(wgp + (size_t)(8 * j) * K + kt + 64,
              &Ws[cur ^ 1][32 * w + 8 * j][0]);
    }
#pragma unroll
    for (int kh = 0; kh < 2; ++kh) {
      int sw = ((q4 + 4 * kh) ^ (ln & 7)) * 8;
      halfx8 bf[2];
#pragma unroll
      for (int ni = 0; ni < 2; ++ni)
        bf[ni] = *(const halfx8*)&Ws[cur][w * 32 + ni * 16 + ln][sw];
#pragma unroll
      for (int mi = 0; mi < 4; ++mi) {
        halfx8 af = *(const halfx8*)&As[cur][mi * 16 + ln][sw];
#pragma unroll
        for (int ni = 0; ni < 2; ++ni)
          acc[mi][ni] = mfma16(af, bf[ni], acc[mi][ni]);
      }
    }
    __syncthreads();  // readers done with buf cur; prefetch into cur^1 drained
  }
  const float qscale = 0.18033688011112042f;  // (1/sqrt(64)) * log2(e)
#pragma unroll
  for (int ni = 0; ni < 2; ++ni) {
    int col = n0 + w * 32 + ni * 16 + ln;
    float bv = bias[col];
    if constexpr (MODE == 1) {
#pragma unroll
      for (int mi = 0; mi < 4; ++mi)
#pragma unroll
        for (int i = 0; i < 4; ++i) {
          int row = m0 + mi * 16 + q4 * 4 + i;
          ((float*)Cv)[(size_t)row * 1024 + col] = acc[mi][ni][i] + bv;
        }
    } else {
      if (col < 1024) {  // Q, pre-scaled for log2-domain softmax
#pragma unroll
        for (int mi = 0; mi < 4; ++mi)
#pragma unroll
          for (int i = 0; i < 4; ++i) {
            int row = m0 + mi * 16 + q4 * 4 + i;
            ((_Float16*)Cv)[(size_t)row * 1024 + col] =
                (_Float16)((acc[mi][ni][i] + bv) * qscale);
          }
      } else if (col < 1088) {  // k_sum
        int ck = col - 1024;
#pragma unroll
        for (int mi = 0; mi < 4; ++mi)
#pragma unroll
          for (int i = 0; i < 4; ++i) {
            int row = m0 + mi * 16 + q4 * 4 + i;
            kbo[(size_t)row * 64 + ck] = (_Float16)(acc[mi][ni][i] + bv);
          }
      } else {  // v_sum, transposed: vtb[(b*64+d)*S + s]
        int d = col - 1088;
#pragma unroll
        for (int mi = 0; mi < 4; ++mi) {
          int row0 = m0 + mi * 16 + q4 * 4;
          int bb = row0 >> 11, sps = row0 & 2047;
          halfx4 o;
#pragma unroll
          for (int i = 0; i < 4; ++i) o[i] = (_Float16)(acc[mi][ni][i] + bv);
          *(halfx4*)&vto[((size_t)((bb << 6) + d)) * S_LEN + sps] = o;
        }
      }
    }
  }
}

// ---------------- flash v6: 32x32x16, 2 s per wave packed in B-cols --------
// B-operand = [Q(s) | Q(s+1)]: col n = si*16 + h. A = K rows (t). C/D layout
// (32x32): col = lane&31, row = (reg&3) + 8*(reg>>2) + 4*(lane>>5).
// P (C-layout) -> PV B-operand entirely via shfl_xor(32) + selects (no LDS).
// Block = 2 waves = 4 s; grid 1024 LPT; gll16 XOR-swizzled K/V staging.
__global__ __launch_bounds__(128, 2) void flash_attn6(
    const _Float16* __restrict__ Qb, const _Float16* __restrict__ kb,
    const _Float16* __restrict__ vtb, _Float16* __restrict__ aob) {
  __shared__ _Float16 Ks[64][64];   // K tile [t][d], XOR-swizzled groups
  __shared__ _Float16 Vt[64][64];   // V^T tile [d][t], XOR-swizzled
  int tid = threadIdx.x;
  int lane = tid & 63, w = tid >> 6;               // w in {0,1}
  int col = lane & 31, hk = lane >> 5;             // col=(si,h), hk = k-half
  int h = lane & 15, si = (lane >> 4) & 1;
  int idx = 1023 - (int)blockIdx.x;                // longest chunks first
  int c = idx >> 1, b = idx & 1;
  int s0 = c * 4;
  int s = s0 + 2 * w + si;
  size_t bS = (size_t)b * S_LEN;

  halfx8 bq[4];  // B[k=d][n=col]: Q[s][h*64 + kd*16 + hk*8 + j]
  {
    const _Float16* qp = Qb + (bS + s) * DIM + h * 64 + hk * 8;
#pragma unroll
    for (int kd = 0; kd < 4; ++kd) bq[kd] = *(const halfx8*)(qp + kd * 16);
  }
  float m_run = -1e30f, l_run = 0.f;
  floatx16 oacc[2] = {};
  int rr = lane >> 3, gg8 = ((lane & 7) ^ rr) * 8;
  const _Float16* kgp = kb + (bS + w * 32 + rr) * 64 + gg8;
  const _Float16* vgp = vtb + ((size_t)b * 64 + w * 32 + rr) * S_LEN + gg8;
  int swb = col & 7;
  int nt = (s0 >> 6) + 1;

  for (int it = 0; it < nt; ++it) {
    int t0 = it << 6;
    __syncthreads();
#pragma unroll
    for (int j = 0; j < 4; ++j) {
      gll16(kgp + (size_t)(t0 + 8 * j) * 64, &Ks[w * 32 + 8 * j][0]);
      gll16(vgp + (size_t)(8 * j) * S_LEN + t0, &Vt[w * 32 + 8 * j][0]);
    }
    __syncthreads();

    // S^T tiles: A = K rows t (2 tiles of 32), k-dim = d (4 mfma)
    floatx16 sf[2];
#pragma unroll
    for (int tt = 0; tt < 2; ++tt) {
      floatx16 z = {};
#pragma unroll
      for (int kd = 0; kd < 4; ++kd) {
        halfx8 ak =
            *(const halfx8*)&Ks[tt * 32 + col][((kd * 2 + hk) ^ swb) * 8];
        z = mfma32(ak, bq[kd], z);
      }
      sf[tt] = z;
    }
    if (it == nt - 1) {  // causal mask; earlier tiles provably all t <= s
      int base = s - t0 - 4 * hk;
#pragma unroll
      for (int tt = 0; tt < 2; ++tt)
#pragma unroll
        for (int r = 0; r < 16; ++r) {
          int cr = (r & 3) + 8 * (r >> 2) + 32 * tt;
          if (cr > base) sf[tt][r] = -1e30f;
        }
    }
    // col-max over t: 32 in-lane + one xor-32 round
    float tm = sf[0][0];
#pragma unroll
    for (int tt = 0; tt < 2; ++tt)
#pragma unroll
      for (int r = 0; r < 16; ++r) tm = fmaxf(tm, sf[tt][r]);
    tm = fmaxf(tm, __shfl_xor(tm, 32));
    float mo = m_run;
    float mn = fmaxf(mo, tm);
    m_run = mn;
    if (__any(tm > mo)) {  // rescale only when some col's max moved
      float alpha = exp2f(mo - mn);
#pragma unroll
      for (int dd = 0; dd < 2; ++dd)
#pragma unroll
        for (int r = 0; r < 16; ++r) oacc[dd][r] *= alpha;
      l_run *= alpha;
    }
    // P = exp2(s - m), packed pairs; row-sum
    float rs = 0.f;
    int pk[16];
#pragma unroll
    for (int tt = 0; tt < 2; ++tt)
#pragma unroll
      for (int i = 0; i < 8; ++i) {
        float p0 = exp2f(sf[tt][2 * i] - mn);
        float p1 = exp2f(sf[tt][2 * i + 1] - mn);
        rs += p0 + p1;
        union { _Float16 hh[2]; int ii; } u;
        u.hh[0] = (_Float16)p0;
        u.hh[1] = (_Float16)p1;
        pk[tt * 8 + i] = u.ii;
      }
    rs += __shfl_xor(rs, 32);
    l_run += rs;
    // PV: B[k=t][n=col] built from C-layout regs via xor-32 shuffle.
    // bp[kt][j]: source half = j>>2, source reg = (j&3) + 4*((2*(kt&1)+hT)&3)
#pragma unroll
    for (int kt = 0; kt < 4; ++kt) {
      int tt = kt >> 1, q0 = 2 * (kt & 1), q1 = q0 + 1;
      int own0 = hk ? pk[tt * 8 + 2 * q1]     : pk[tt * 8 + 2 * q0];
      int own1 = hk ? pk[tt * 8 + 2 * q1 + 1] : pk[tt * 8 + 2 * q0 + 1];
      int snd0 = hk ? pk[tt * 8 + 2 * q0]     : pk[tt * 8 + 2 * q1];
      int snd1 = hk ? pk[tt * 8 + 2 * q0 + 1] : pk[tt * 8 + 2 * q1 + 1];
      int rcv0 = __shfl_xor(snd0, 32);
      int rcv1 = __shfl_xor(snd1, 32);
      union { int ii[4]; halfx8 hh; } u;
      u.ii[0] = hk ? rcv0 : own0;
      u.ii[1] = hk ? rcv1 : own1;
      u.ii[2] = hk ? own0 : rcv0;
      u.ii[3] = hk ? own1 : rcv1;
#pragma unroll
      for (int dd = 0; dd < 2; ++dd) {
        halfx8 av =
            *(const halfx8*)&Vt[dd * 32 + col][((kt * 2 + hk) ^ swb) * 8];
        oacc[dd] = mfma32(av, u.hh, oacc[dd]);
      }
    }
  }
  // epilogue: O^T[d][col]: d = dd*32 + rg*8 + hk*4 + (r&3)
  float inv = 1.0f / l_run;
#pragma unroll
  for (int dd = 0; dd < 2; ++dd)
#pragma unroll
    for (int rg = 0; rg < 4; ++rg) {
      halfx4 o;
#pragma unroll
      for (int i2 = 0; i2 < 4; ++i2)
        o[i2] = (_Float16)(oacc[dd][rg * 4 + i2] * inv);
      *(halfx4*)(aob + (bS + s) * DIM + h * 64 + dd * 32 + rg * 8 + hk * 4) = o;
    }
}

extern "C" void kernel_launch(void* const* d_in, const int* in_sizes, int n_in,
                              void* d_out, int out_size, void* d_ws,
                              size_t ws_size, hipStream_t stream) {
  const float* x    = (const float*)d_in[0];
  const float* wqkv = (const float*)d_in[1];
  const float* bqkv = (const float*)d_in[2];
  const float* wout = (const float*)d_in[3];
  const float* bout = (const float*)d_in[4];
  float* out = (float*)d_out;
  char* ws = (char*)d_ws;
  _Float16* xb    = (_Float16*)(ws);                               // 8 MB
  _Float16* qb    = (_Float16*)(ws + (8u << 20));                  // 8 MB
  _Float16* aob   = (_Float16*)(ws + (16u << 20));                 // 8 MB
  _Float16* kb    = (_Float16*)(ws + (24u << 20));                 // 512 KB
  _Float16* vtb   = (_Float16*)(ws + (24u << 20) + (512u << 10));  // 512 KB
  _Float16* wcomb = (_Float16*)(ws + (25u << 20));                 // 2.25 MB
  _Float16* woutb = (_Float16*)(ws + (27u << 20) + (512u << 10));  // 2 MB
  float*    bcomb = (float*)(ws + (29u << 20) + (512u << 10));     // 4.6 KB

  hipLaunchKernelGGL(prep_all, dim3(6656), dim3(256), 0, stream,
                     x, wqkv, bqkv, wout, xb, wcomb, woutb, bcomb);
  hipLaunchKernelGGL((gemm_big<0>), dim3(64, 9), dim3(256), 0, stream,
                     xb, wcomb, bcomb, (void*)qb, kb, vtb);
  hipLaunchKernelGGL(flash_attn6, dim3(1024), dim3(128), 0, stream,
                     qb, kb, vtb, aob);
  hipLaunchKernelGGL((gemm_big<1>), dim3(64, 8), dim3(256), 0, stream,
                     aob, woutb, bout, (void*)out, nullptr, nullptr);
}

// Round 7
// 169.376 us; speedup vs baseline: 1.0979x; 1.0979x over previous
//
#include <hip/hip_runtime.h>

// Problem: B=2, S=2048, D=1024, H=16, HD=64. fp32 in/out.
// Pipeline exploits head-summed K/V: k_sum = x @ (sum_h Wk_h)^T + sum_h bk_h.
//  1. prep_all:    x, Wout -> f16; wcomb = [Wq; Wred] f16 (1152x1024); bcomb
//  2. gemm_t2<0>:  [Q*scale | k_sum | v_sum^T] = x @ wcomb^T + bcomb (N=1152)
//  3. flash_attn7: R5 shape (1 s/wave, 4-wave blocks), 128-t staging depth
//  4. gemm_t2<1>:  out = ao @ Wout^T + bout   (4096x1024x1024) -> f32

#define S_LEN 2048
#define DIM 1024

using floatx4 = __attribute__((ext_vector_type(4))) float;
using halfx8  = __attribute__((ext_vector_type(8))) _Float16;
using halfx4  = __attribute__((ext_vector_type(4))) _Float16;

__device__ __forceinline__ floatx4 mfma16(halfx8 a, halfx8 b, floatx4 c) {
  return __builtin_amdgcn_mfma_f32_16x16x32_f16(a, b, c, 0, 0, 0);
}

// async global->LDS, 16B per lane; lds dst is wave-uniform base + lane*16
__device__ __forceinline__ void gll16(const void* g, void* l) {
  __builtin_amdgcn_global_load_lds(
      (const __attribute__((address_space(1))) void*)g,
      (__attribute__((address_space(3))) void*)l, 16, 0, 0);
}

// ---------------- prep: conversions + combined weights ----------------
__global__ __launch_bounds__(256) void prep_all(
    const float* __restrict__ x, const float* __restrict__ wqkv,
    const float* __restrict__ bqkv, const float* __restrict__ wout,
    _Float16* __restrict__ xb, _Float16* __restrict__ wcomb,
    _Float16* __restrict__ woutb, float* __restrict__ bcomb) {
  int bx = blockIdx.x;
  if (bx < 6144) {
    size_t i4 = ((size_t)bx * 256 + threadIdx.x) * 4;
    const float* src;
    _Float16* dst;
    size_t off;
    if (i4 < 4194304) { src = x; dst = xb; off = i4; }
    else if (i4 < 5242880) { src = wqkv; dst = wcomb; off = i4 - 4194304; }
    else { src = wout; dst = woutb; off = i4 - 5242880; }
    float4 v = *(const float4*)(src + off);
    halfx4 o;
    o[0] = (_Float16)v.x; o[1] = (_Float16)v.y;
    o[2] = (_Float16)v.z; o[3] = (_Float16)v.w;
    *(halfx4*)(dst + off) = o;
  } else {
    int gid = (bx - 6144) * 256 + threadIdx.x;  // 131072 threads
    int c = gid >> 10, j = gid & 1023;
    int row0 = (c < 64) ? (1024 + c) : (2048 + c - 64);
    float s = 0.f;
#pragma unroll
    for (int h = 0; h < 16; ++h) s += wqkv[(size_t)(row0 + h * 64) * 1024 + j];
    wcomb[(size_t)1024 * 1024 + gid] = (_Float16)s;
    if (gid < 1024) bcomb[gid] = bqkv[gid];
    if (gid < 128) {
      int b0 = (gid < 64) ? (1024 + gid) : (2048 + gid - 64);
      float sb = 0.f;
#pragma unroll
      for (int h = 0; h < 16; ++h) sb += bqkv[b0 + h * 64];
      bcomb[1024 + gid] = sb;
    }
  }
}

// ------- gemm_t2: 128M x 128N tile (m97-style), BK=64, 2 barriers/step -----
// Wave w -> 64x64 quadrant: rows (w&1)*64, cols (w>>1)*64; 4x4 16x16 frags.
// gll16 staging with XOR col-group swizzle (row r group g at g^(r&7)).
// MODE 0: N=1152 fused epilogue -> qb (*scale), kb, vtb(V^T). MODE 1: f32 out.
template <int MODE>
__global__ __launch_bounds__(256, 2) void gemm_t2(
    const _Float16* __restrict__ A, const _Float16* __restrict__ W,
    const float* __restrict__ bias, void* __restrict__ Cv,
    _Float16* __restrict__ kbo, _Float16* __restrict__ vto) {
  const int K = 1024;
  __shared__ _Float16 As[128][64];  // 16 KB
  __shared__ _Float16 Ws[128][64];  // 16 KB
  int tid = threadIdx.x;
  int lane = tid & 63, w = tid >> 6, ln = lane & 15, q4 = lane >> 4;
  int m0 = blockIdx.x * 128, n0 = blockIdx.y * 128;
  int mh = (w & 1) * 64, nh = (w >> 1) * 64;
  int rr = lane >> 3, gg = ((lane & 7) ^ rr) * 8;  // staging lane row/col
  const _Float16* agp = A + (size_t)(m0 + w * 32 + rr) * K + gg;
  const _Float16* wgp = W + (size_t)(n0 + w * 32 + rr) * K + gg;
  floatx4 acc[4][4] = {};
  for (int kt = 0; kt < K; kt += 64) {
    __syncthreads();  // readers done with previous tile
#pragma unroll
    for (int j = 0; j < 4; ++j) {
      gll16(agp + (size_t)(8 * j) * K + kt, &As[w * 32 + 8 * j][0]);
      gll16(wgp + (size_t)(8 * j) * K + kt, &Ws[w * 32 + 8 * j][0]);
    }
    __syncthreads();  // staging visible
#pragma unroll
    for (int kh = 0; kh < 2; ++kh) {
      int sw = ((q4 + 4 * kh) ^ (ln & 7)) * 8;
      halfx8 bf[4];
#pragma unroll
      for (int nf = 0; nf < 4; ++nf)
        bf[nf] = *(const halfx8*)&Ws[nh + nf * 16 + ln][sw];
#pragma unroll
      for (int mf = 0; mf < 4; ++mf) {
        halfx8 af = *(const halfx8*)&As[mh + mf * 16 + ln][sw];
#pragma unroll
        for (int nf = 0; nf < 4; ++nf)
          acc[mf][nf] = mfma16(af, bf[nf], acc[mf][nf]);
      }
    }
  }
  const float qscale = 0.18033688011112042f;  // (1/sqrt(64)) * log2(e)
#pragma unroll
  for (int nf = 0; nf < 4; ++nf) {
    int col = n0 + nh + nf * 16 + ln;
    float bv = bias[col];
    if constexpr (MODE == 1) {
#pragma unroll
      for (int mf = 0; mf < 4; ++mf)
#pragma unroll
        for (int i = 0; i < 4; ++i) {
          int row = m0 + mh + mf * 16 + q4 * 4 + i;
          ((float*)Cv)[(size_t)row * 1024 + col] = acc[mf][nf][i] + bv;
        }
    } else {
      if (col < 1024) {  // Q, pre-scaled for log2-domain softmax
#pragma unroll
        for (int mf = 0; mf < 4; ++mf)
#pragma unroll
          for (int i = 0; i < 4; ++i) {
            int row = m0 + mh + mf * 16 + q4 * 4 + i;
            ((_Float16*)Cv)[(size_t)row * 1024 + col] =
                (_Float16)((acc[mf][nf][i] + bv) * qscale);
          }
      } else if (col < 1088) {  // k_sum
        int ck = col - 1024;
#pragma unroll
        for (int mf = 0; mf < 4; ++mf)
#pragma unroll
          for (int i = 0; i < 4; ++i) {
            int row = m0 + mh + mf * 16 + q4 * 4 + i;
            kbo[(size_t)row * 64 + ck] = (_Float16)(acc[mf][nf][i] + bv);
          }
      } else {  // v_sum, transposed: vtb[(b*64+d)*S + s]
        int d = col - 1088;
#pragma unroll
        for (int mf = 0; mf < 4; ++mf) {
          int row0 = m0 + mh + mf * 16 + q4 * 4;
          int bb = row0 >> 11, sps = row0 & 2047;
          halfx4 o;
#pragma unroll
          for (int i = 0; i < 4; ++i) o[i] = (_Float16)(acc[mf][nf][i] + bv);
          *(halfx4*)&vto[((size_t)((bb << 6) + d)) * S_LEN + sps] = o;
        }
      }
    }
  }
}

// ---------------- flash v7: R5 shape, 128-t staging depth ----------------
// Wave = one s, all 16 heads; block = 4 s. Stage 128 t per barrier-pair,
// then two 64-t sub-tiles back-to-back (no barrier between). Q pre-scaled
// (log2 domain). Grid 1024 LPT; gll16 XOR-swizzled staging; Ps pitch 72.
__global__ __launch_bounds__(256, 4) void flash_attn7(
    const _Float16* __restrict__ Qb, const _Float16* __restrict__ kb,
    const _Float16* __restrict__ vtb, _Float16* __restrict__ aob) {
  __shared__ _Float16 Ks[128][64];    // K tile [t][d], XOR-swizzled groups
  __shared__ _Float16 Vt[64][128];    // V^T tile [d][t], per-64-half swizzle
  __shared__ _Float16 Ps[4][16][72];  // per-wave P[h][t]
  int tid = threadIdx.x;
  int lane = tid & 63, w = tid >> 6, ln = lane & 15, q4 = lane >> 4;
  int idx = 1023 - (int)blockIdx.x;   // longest chunks first
  int c = idx >> 1, b = idx & 1;
  int s0 = c * 4;
  int s = s0 + w;
  size_t bS = (size_t)b * S_LEN;

  const _Float16* qp = Qb + (bS + s) * DIM + ln * 64 + q4 * 8;
  halfx8 bq0 = *(const halfx8*)qp, bq1 = *(const halfx8*)(qp + 32);

  float m_run = -1e30f, l_run = 0.f;
  floatx4 oacc[4] = {};

  // K staging: wave w covers rows w*32..+31; lane: row +=(lane>>3), grp^row
  int rr = lane >> 3, ggk = ((lane & 7) ^ rr) * 8;
  const _Float16* kgp = kb + (bS + w * 32 + rr) * 64 + ggk;
  // V staging: wave w covers d-rows w*16..+15; lane: row += lane>>4,
  // t-col = half*64 + (g ^ (row&7))*8, g = lane&7, half = (lane>>3)&1
  int vrow = (lane >> 4);
  int vhalf = (lane >> 3) & 1, vg = lane & 7;
  const _Float16* vgp[4];
#pragma unroll
  for (int j = 0; j < 4; ++j) {
    int row = w * 16 + 4 * j + vrow;
    vgp[j] = vtb + ((size_t)b * 64 + row) * S_LEN + vhalf * 64 +
             ((vg ^ (row & 7)) * 8);
  }
  int swk0 = (q4 ^ (ln & 7)) * 8;
  int swk1 = ((q4 + 4) ^ (ln & 7)) * 8;
  _Float16* Pw = &Ps[w][0][0];
  int nt = (s0 >> 7) + 1;

  for (int it = 0; it < nt; ++it) {
    int t0 = it << 7;
    __syncthreads();
#pragma unroll
    for (int j = 0; j < 4; ++j) {
      gll16(kgp + (size_t)(t0 + 8 * j) * 64, &Ks[w * 32 + 8 * j][0]);
      gll16(vgp[j] + t0, &Vt[w * 16 + 4 * j][0]);
    }
    __syncthreads();

#pragma unroll
    for (int tq = 0; tq < 2; ++tq) {
      int t0q = t0 + tq * 64;
      if (t0q > s) break;  // wave-uniform
      // S^T = K Q^T (log2 domain): frag tf rows t = t0q + tf*16 + ln
      floatx4 sf[4];
#pragma unroll
      for (int tf = 0; tf < 4; ++tf) {
        halfx8 ak0 = *(const halfx8*)&Ks[tq * 64 + tf * 16 + ln][swk0];
        halfx8 ak1 = *(const halfx8*)&Ks[tq * 64 + tf * 16 + ln][swk1];
        floatx4 z = {};
        z = mfma16(ak0, bq0, z);
        sf[tf] = mfma16(ak1, bq1, z);
      }
      if (t0q + 63 > s) {  // causal mask on the boundary sub-tile only
#pragma unroll
        for (int tf = 0; tf < 4; ++tf)
#pragma unroll
          for (int i = 0; i < 4; ++i) {
            int t = t0q + tf * 16 + q4 * 4 + i;
            if (t > s) sf[tf][i] = -1e30f;
          }
      }
      float tm = fmaxf(fmaxf(sf[0][0], sf[0][1]), fmaxf(sf[0][2], sf[0][3]));
#pragma unroll
      for (int tf = 1; tf < 4; ++tf)
        tm = fmaxf(tm, fmaxf(fmaxf(sf[tf][0], sf[tf][1]),
                             fmaxf(sf[tf][2], sf[tf][3])));
      tm = fmaxf(tm, __shfl_xor(tm, 16));
      tm = fmaxf(tm, __shfl_xor(tm, 32));
      float mn = fmaxf(m_run, tm);
      float alpha = exp2f(m_run - mn);
      m_run = mn;
      float rs = 0.f;
#pragma unroll
      for (int tf = 0; tf < 4; ++tf) {
        float p0 = exp2f(sf[tf][0] - mn), p1 = exp2f(sf[tf][1] - mn);
        float p2 = exp2f(sf[tf][2] - mn), p3 = exp2f(sf[tf][3] - mn);
        rs += (p0 + p1) + (p2 + p3);
        halfx4 pk;
        pk[0] = (_Float16)p0; pk[1] = (_Float16)p1;
        pk[2] = (_Float16)p2; pk[3] = (_Float16)p3;
        *(halfx4*)&Pw[ln * 72 + tf * 16 + q4 * 4] = pk;
      }
      rs += __shfl_xor(rs, 16);
      rs += __shfl_xor(rs, 32);
      l_run = l_run * alpha + rs;
      halfx8 bp0 = *(const halfx8*)&Pw[ln * 72 + q4 * 8];
      halfx8 bp1 = *(const halfx8*)&Pw[ln * 72 + 32 + q4 * 8];
#pragma unroll
      for (int n2 = 0; n2 < 4; ++n2) {
        halfx8 av0 = *(const halfx8*)&Vt[n2 * 16 + ln][tq * 64 + swk0];
        halfx8 av1 = *(const halfx8*)&Vt[n2 * 16 + ln][tq * 64 + swk1];
#pragma unroll
        for (int i = 0; i < 4; ++i) oacc[n2][i] *= alpha;
        oacc[n2] = mfma16(av0, bp0, oacc[n2]);
        oacc[n2] = mfma16(av1, bp1, oacc[n2]);
      }
    }
  }
  // epilogue: O^T frag n2: h=ln, d=n2*16+q4*4+i
  float inv = 1.0f / l_run;
#pragma unroll
  for (int n2 = 0; n2 < 4; ++n2) {
    halfx4 o;
#pragma unroll
    for (int i = 0; i < 4; ++i) o[i] = (_Float16)(oacc[n2][i] * inv);
    *(halfx4*)(aob + (bS + s) * DIM + ln * 64 + n2 * 16 + q4 * 4) = o;
  }
}

extern "C" void kernel_launch(void* const* d_in, const int* in_sizes, int n_in,
                              void* d_out, int out_size, void* d_ws,
                              size_t ws_size, hipStream_t stream) {
  const float* x    = (const float*)d_in[0];
  const float* wqkv = (const float*)d_in[1];
  const float* bqkv = (const float*)d_in[2];
  const float* wout = (const float*)d_in[3];
  const float* bout = (const float*)d_in[4];
  float* out = (float*)d_out;
  char* ws = (char*)d_ws;
  _Float16* xb    = (_Float16*)(ws);                               // 8 MB
  _Float16* qb    = (_Float16*)(ws + (8u << 20));                  // 8 MB
  _Float16* aob   = (_Float16*)(ws + (16u << 20));                 // 8 MB
  _Float16* kb    = (_Float16*)(ws + (24u << 20));                 // 512 KB
  _Float16* vtb   = (_Float16*)(ws + (24u << 20) + (512u << 10));  // 512 KB
  _Float16* wcomb = (_Float16*)(ws + (25u << 20));                 // 2.25 MB
  _Float16* woutb = (_Float16*)(ws + (27u << 20) + (512u << 10));  // 2 MB
  float*    bcomb = (float*)(ws + (29u << 20) + (512u << 10));     // 4.6 KB

  hipLaunchKernelGGL(prep_all, dim3(6656), dim3(256), 0, stream,
                     x, wqkv, bqkv, wout, xb, wcomb, woutb, bcomb);
  hipLaunchKernelGGL((gemm_t2<0>), dim3(32, 9), dim3(256), 0, stream,
                     xb, wcomb, bcomb, (void*)qb, kb, vtb);
  hipLaunchKernelGGL(flash_attn7, dim3(1024), dim3(256), 0, stream,
                     qb, kb, vtb, aob);
  hipLaunchKernelGGL((gemm_t2<1>), dim3(32, 8), dim3(256), 0, stream,
                     aob, woutb, bout, (void*)out, nullptr, nullptr);
}